// Round 3
// baseline (237.140 us; speedup 1.0000x reference)
//
#include <hip/hip_runtime.h>

typedef __attribute__((ext_vector_type(8))) __bf16 bf16x8;
typedef __attribute__((ext_vector_type(4))) __bf16 bf16x4;
typedef __attribute__((ext_vector_type(4))) float f32x4;
typedef __attribute__((ext_vector_type(8))) unsigned short us8;

constexpr float SCALE_L2E = 0.08838834764831845f * 1.4426950408889634f; // (1/sqrt(128))*log2(e)

__device__ __forceinline__ unsigned short f2bf(float f) {
  unsigned int u = __float_as_uint(f);
  u = (u + 0x7FFFu + ((u >> 16) & 1u)) >> 16;
  return (unsigned short)u;
}

__device__ __forceinline__ void gl_lds16(const void* g, void* l) {
  __builtin_amdgcn_global_load_lds(
      (__attribute__((address_space(1))) void*)const_cast<void*>(g),
      (__attribute__((address_space(3))) void*)l, 16, 0, 0);
}

// ---------------- K0: f32 -> bf16 convert (query + 3 weight matrices) ----------------
__global__ __launch_bounds__(256) void k_convert(
    const float* __restrict__ q, const float* __restrict__ wq,
    const float* __restrict__ wk, const float* __restrict__ wv,
    unsigned short* __restrict__ xb, unsigned short* __restrict__ wb) {
  long i = ((long)blockIdx.x * 256 + threadIdx.x) * 8;
  const float* s; unsigned short* d;
  if (i < 4194304)      { s = q  + i;             d = xb + i; }
  else if (i < 5242880) { s = wq + (i - 4194304); d = wb + (i - 4194304); }
  else if (i < 6291456) { s = wk + (i - 5242880); d = wb + 1048576 + (i - 5242880); }
  else                  { s = wv + (i - 6291456); d = wb + 2097152 + (i - 6291456); }
  float4 a = *(const float4*)s;
  float4 b = *(const float4*)(s + 4);
  us8 r;
  r[0]=f2bf(a.x); r[1]=f2bf(a.y); r[2]=f2bf(a.z); r[3]=f2bf(a.w);
  r[4]=f2bf(b.x); r[5]=f2bf(b.y); r[6]=f2bf(b.z); r[7]=f2bf(b.w);
  *(us8*)d = r;
}

// ---------------- K1: projection GEMM  C = X @ W^T + b  (z selects q/k/v) ----------------
// z==0 (q): sign twist applied, row-major out. z==1 (k): row-major out.
// z==2 (v): written DIRECTLY transposed into vt[bh*128+d][l] (packed 8B stores).
__global__ __launch_bounds__(256) void k_proj(
    const unsigned short* __restrict__ xb, const unsigned short* __restrict__ wb,
    const float* __restrict__ bq, const float* __restrict__ bk, const float* __restrict__ bv,
    unsigned short* __restrict__ oq, unsigned short* __restrict__ ok_, unsigned short* __restrict__ vt) {
  __shared__ unsigned short As[4096]; // 128 rows x 32 k
  __shared__ unsigned short Bs[4096];
  const int t = threadIdx.x;
  const int wave = t >> 6, lane = t & 63;
  const int lrow = lane & 15, grp = lane >> 4;
  const int z = blockIdx.z;
  const unsigned short* w = wb + (size_t)z * 1048576;
  const float* bias = (z == 0) ? bq : ((z == 1) ? bk : bv);

  const unsigned short* asrc = xb + ((size_t)(blockIdx.y * 128 + (t >> 2)) * 1024 + (t & 3) * 8);
  const unsigned short* bsrc = w  + ((size_t)(blockIdx.x * 128 + (t >> 2)) * 1024 + (t & 3) * 8);

  f32x4 acc[4][4] = {};
  for (int kt = 0; kt < 32; ++kt) {
    gl_lds16(asrc + kt*32,              &As[t*8]);
    gl_lds16(asrc + kt*32 + 64*1024,    &As[2048 + t*8]);
    gl_lds16(bsrc + kt*32,              &Bs[t*8]);
    gl_lds16(bsrc + kt*32 + 64*1024,    &Bs[2048 + t*8]);
    __syncthreads();
    const int wr = wave >> 1, wc = wave & 1;
    bf16x8 af[4], bf[4];
#pragma unroll
    for (int mf = 0; mf < 4; ++mf)
      af[mf] = *(const bf16x8*)&As[(wr*64 + mf*16 + lrow)*32 + grp*8];
#pragma unroll
    for (int nf = 0; nf < 4; ++nf)
      bf[nf] = *(const bf16x8*)&Bs[(wc*64 + nf*16 + lrow)*32 + grp*8];
#pragma unroll
    for (int mf = 0; mf < 4; ++mf)
#pragma unroll
      for (int nf = 0; nf < 4; ++nf)
        acc[mf][nf] = __builtin_amdgcn_mfma_f32_16x16x32_bf16(af[mf], bf[nf], acc[mf][nf], 0, 0, 0);
    __syncthreads();
  }
  const int wr = wave >> 1, wc = wave & 1;
  if (z == 2) {
    // transposed store: vt[((b*8+h)*128 + dcol)][l], 4 consecutive l per lane
#pragma unroll
    for (int nf = 0; nf < 4; ++nf) {
      const int col = blockIdx.x*128 + wc*64 + nf*16 + lrow;
      const int h = col >> 7, dc = col & 127;
      const float bsv = bias[col];
#pragma unroll
      for (int mf = 0; mf < 4; ++mf) {
        const int r0 = blockIdx.y*128 + wr*64 + mf*16 + grp*4;
        const int bb = r0 >> 11, l0 = r0 & 2047;
        bf16x4 pv;
#pragma unroll
        for (int i = 0; i < 4; ++i) pv[i] = (__bf16)(acc[mf][nf][i] + bsv);
        *(bf16x4*)&vt[((size_t)((bb*8 + h)*128 + dc))*2048 + l0] = pv;
      }
    }
  } else {
    unsigned short* dst = (z == 0) ? oq : ok_;
    const float sign = (z == 0 && (lane & 7) >= 4) ? -1.0f : 1.0f;
#pragma unroll
    for (int nf = 0; nf < 4; ++nf) {
      const int col = blockIdx.x*128 + wc*64 + nf*16 + lrow;
      const float bsv = bias[col];
#pragma unroll
      for (int mf = 0; mf < 4; ++mf)
#pragma unroll
        for (int i = 0; i < 4; ++i) {
          const int row = blockIdx.y*128 + wr*64 + mf*16 + grp*4 + i;
          dst[(size_t)row*1024 + col] = f2bf((acc[mf][nf][i] + bsv) * sign);
        }
    }
  }
}

// ---------------- K3: fused attention out + rowsum (no-max online softmax) ----------------
// QBLK=32 per block, grid 64x16 = 1024 blocks (4 blocks/CU). XCD-swizzled so each
// XCD owns 2 (b,h) pairs -> K+V (2MB) L2-resident. K fragments double-buffered one
// iteration ahead; V fragments issued at QK start, consumed after the barrier.
__global__ __launch_bounds__(256, 4) void k_attn_out(
    const unsigned short* __restrict__ qw, const unsigned short* __restrict__ kb,
    const unsigned short* __restrict__ vt, float* __restrict__ outp,
    float* __restrict__ rsw) {
  __shared__ unsigned short P[32*72];   // [l][m], stride 72
  __shared__ float red[160];
  const int bid = blockIdx.x + (blockIdx.y << 6);
  const int xcd = bid & 7, slot = bid >> 3;
  const int bh = (xcd << 1) | (slot >> 6);   // 2 bh per XCD
  const int lt = slot & 63;                  // 0..63 (32-row q tile)
  const int b = bh >> 3, h = bh & 7;
  const int t = threadIdx.x;
  const int wave = t >> 6, lane = t & 63;
  const int lrow = lane & 15, grp = lane >> 4;

  const unsigned short* qb  = qw + ((size_t)b*2048*1024 + (size_t)h*128);
  const unsigned short* kbp = kb + ((size_t)b*2048*1024 + (size_t)h*128);
  const unsigned short* vtp = vt + ((size_t)bh*128*2048);

  bf16x8 qf[2][4];
#pragma unroll
  for (int lf = 0; lf < 2; ++lf) {
    const size_t roff = (size_t)(lt*32 + lf*16 + lrow) * 1024;
#pragma unroll
    for (int ks = 0; ks < 4; ++ks)
      qf[lf][ks] = *(const bf16x8*)&qb[roff + ks*32 + grp*8];
  }

  f32x4 oacc[2][2] = {};
  float rs[2] = {0.f, 0.f};

  auto loadK = [&](bf16x8 (&kf)[4], int mt) {
    const size_t mrow = (size_t)(mt*64 + wave*16 + lrow) * 1024;
#pragma unroll
    for (int ks = 0; ks < 4; ++ks)
      kf[ks] = *(const bf16x8*)&kbp[mrow + ks*32 + grp*8];
  };

  auto process = [&](bf16x8 (&kf)[4], int mt) {
    bf16x8 vf[2][2];   // issued now, consumed after the barrier (latency hidden by QK)
#pragma unroll
    for (int ks2 = 0; ks2 < 2; ++ks2)
#pragma unroll
      for (int df = 0; df < 2; ++df)
        vf[ks2][df] = *(const bf16x8*)&vtp[(size_t)(wave*32 + df*16 + lrow)*2048 + mt*64 + ks2*32 + grp*8];
    f32x4 s[2] = {};
#pragma unroll
    for (int ks = 0; ks < 4; ++ks)
#pragma unroll
      for (int lf = 0; lf < 2; ++lf)
        s[lf] = __builtin_amdgcn_mfma_f32_16x16x32_bf16(kf[ks], qf[lf][ks], s[lf], 0, 0, 0);
#pragma unroll
    for (int lf = 0; lf < 2; ++lf) {
      float e0 = __builtin_amdgcn_exp2f(s[lf][0] * SCALE_L2E);
      float e1 = __builtin_amdgcn_exp2f(s[lf][1] * SCALE_L2E);
      float e2 = __builtin_amdgcn_exp2f(s[lf][2] * SCALE_L2E);
      float e3 = __builtin_amdgcn_exp2f(s[lf][3] * SCALE_L2E);
      rs[lf] += (e0 + e1) + (e2 + e3);
      bf16x4 pk;
      pk[0] = (__bf16)e0; pk[1] = (__bf16)e1; pk[2] = (__bf16)e2; pk[3] = (__bf16)e3;
      *(bf16x4*)&P[(lf*16 + lrow)*72 + wave*16 + grp*4] = pk;
    }
    __syncthreads();
#pragma unroll
    for (int ks2 = 0; ks2 < 2; ++ks2) {
      bf16x8 pa[2];
#pragma unroll
      for (int lf = 0; lf < 2; ++lf)
        pa[lf] = *(const bf16x8*)&P[(lf*16 + lrow)*72 + ks2*32 + grp*8];
#pragma unroll
      for (int df = 0; df < 2; ++df)
#pragma unroll
        for (int lf = 0; lf < 2; ++lf)
          oacc[lf][df] = __builtin_amdgcn_mfma_f32_16x16x32_bf16(pa[lf], vf[ks2][df], oacc[lf][df], 0, 0, 0);
    }
    __syncthreads();
  };

  bf16x8 kfA[4], kfB[4];
  loadK(kfA, 0);
  for (int mt = 0; mt < 32; mt += 2) {
    loadK(kfB, mt + 1);
    process(kfA, mt);
    if (mt + 2 < 32) loadK(kfA, mt + 2);
    process(kfB, mt + 1);
  }

  rs[0] += __shfl_xor(rs[0], 16, 64); rs[0] += __shfl_xor(rs[0], 32, 64);
  rs[1] += __shfl_xor(rs[1], 16, 64); rs[1] += __shfl_xor(rs[1], 32, 64);
  if (lane < 16) { red[wave*32 + lane] = rs[0]; red[wave*32 + 16 + lane] = rs[1]; }
  __syncthreads();
  if (t < 32) {
    float tot = (red[t] + red[32 + t]) + (red[64 + t] + red[96 + t]);
    rsw[(size_t)bh*2048 + lt*32 + t] = tot;
    red[128 + t] = 1.0f / tot;
  }
  __syncthreads();
#pragma unroll
  for (int lf = 0; lf < 2; ++lf)
#pragma unroll
    for (int i = 0; i < 4; ++i) {
      const int l = lf*16 + grp*4 + i;
      const float iv = red[128 + l];
      const size_t rowo = (size_t)(b*2048 + lt*32 + l) * 1024 + h*128;
#pragma unroll
      for (int df = 0; df < 2; ++df)
        outp[rowo + wave*32 + df*16 + lrow] = oacc[lf][df][i] * iv;
    }
}

// ---------------- K4: head-mean attention weights (LDS-staged GEMM version) ----------------
__global__ __launch_bounds__(256) void k_attn_mean(
    const unsigned short* __restrict__ qw, const unsigned short* __restrict__ kb,
    const float* __restrict__ rsw, float* __restrict__ meanp) {
  __shared__ unsigned short Qs[128*128];   // 32 KB
  __shared__ unsigned short Ks[128*128];   // 32 KB
  __shared__ float inv_s[8*128];           // 4 KB
  const int mt = blockIdx.x;   // 0..15
  const int lt = blockIdx.y;   // 0..15
  const int b  = blockIdx.z;   // 0..1
  const int t = threadIdx.x;
  const int wave = t >> 6, lane = t & 63;
  const int lrow = lane & 15, grp = lane >> 4;
  const int wl = wave >> 1, wm = wave & 1;
  const int trow = t >> 4;     // 0..15 (staging row-within-16)
  const int tcol = t & 15;     // staging 16B-granule column

  for (int idx = t; idx < 1024; idx += 256) {
    int hh = idx >> 7, ll = idx & 127;
    inv_s[idx] = 1.0f / rsw[(size_t)(b*8 + hh)*2048 + lt*128 + ll];
  }

  f32x4 acc[4][4] = {};

  for (int h = 0; h < 8; ++h) {
    __syncthreads();   // previous iteration's LDS reads done (also fences inv_s at h=0)
    const unsigned short* qbase = qw + ((size_t)(b*2048 + lt*128) * 1024 + h*128);
    const unsigned short* kbase = kb + ((size_t)(b*2048 + mt*128) * 1024 + h*128);
#pragma unroll
    for (int i = 0; i < 8; ++i) {
      const int row = i*16 + trow;
      const int sc = (tcol ^ (row & 7)) * 8;   // swizzled source col (us units)
      gl_lds16(qbase + (size_t)row*1024 + sc, &Qs[i*2048 + t*8]);
      gl_lds16(kbase + (size_t)row*1024 + sc, &Ks[i*2048 + t*8]);
    }
    __syncthreads();   // staging complete

    f32x4 s[4][4] = {};
#pragma unroll
    for (int ks = 0; ks < 4; ++ks) {
      bf16x8 af[4], bf[4];
#pragma unroll
      for (int lf = 0; lf < 4; ++lf) {
        const int row = wl*64 + lf*16 + lrow;
        af[lf] = *(const bf16x8*)&Qs[row*128 + ((ks*32 + grp*8) ^ ((row & 7) << 3))];
      }
#pragma unroll
      for (int mf = 0; mf < 4; ++mf) {
        const int row = wm*64 + mf*16 + lrow;
        bf[mf] = *(const bf16x8*)&Ks[row*128 + ((ks*32 + grp*8) ^ ((row & 7) << 3))];
      }
#pragma unroll
      for (int lf = 0; lf < 4; ++lf)
#pragma unroll
        for (int mf = 0; mf < 4; ++mf)
          s[lf][mf] = __builtin_amdgcn_mfma_f32_16x16x32_bf16(af[lf], bf[mf], s[lf][mf], 0, 0, 0);
    }
#pragma unroll
    for (int lf = 0; lf < 4; ++lf)
#pragma unroll
      for (int i = 0; i < 4; ++i) {
        const float iv = inv_s[h*128 + wl*64 + lf*16 + grp*4 + i];
#pragma unroll
        for (int mf = 0; mf < 4; ++mf)
          acc[lf][mf][i] += __builtin_amdgcn_exp2f(s[lf][mf][i] * SCALE_L2E) * iv;
      }
  }

#pragma unroll
  for (int lf = 0; lf < 4; ++lf)
#pragma unroll
    for (int i = 0; i < 4; ++i) {
      const int l = lt*128 + wl*64 + lf*16 + grp*4 + i;
      const size_t rowo = (size_t)(b*2048 + l) * 2048;
#pragma unroll
      for (int mf = 0; mf < 4; ++mf)
        meanp[rowo + mt*128 + wm*64 + mf*16 + lrow] = acc[lf][mf][i] * 0.125f;
    }
}

extern "C" void kernel_launch(void* const* d_in, const int* in_sizes, int n_in,
                              void* d_out, int out_size, void* d_ws, size_t ws_size,
                              hipStream_t stream) {
  (void)in_sizes; (void)n_in; (void)out_size; (void)ws_size;
  const float* query = (const float*)d_in[0];
  const float* Wq = (const float*)d_in[1];
  const float* bq = (const float*)d_in[2];
  const float* Wk = (const float*)d_in[3];
  const float* bk = (const float*)d_in[4];
  const float* Wv = (const float*)d_in[5];
  const float* bv = (const float*)d_in[6];
  float* outp  = (float*)d_out;
  float* meanp = outp + 4194304;           // (B,L,DM) then (B,L,L)

  char* ws = (char*)d_ws;
  unsigned short* xb  = (unsigned short*)(ws);              // 8.4 MB
  unsigned short* wb  = (unsigned short*)(ws + 8388608);    // 6.3 MB (Wq,Wk,Wv)
  unsigned short* qws = (unsigned short*)(ws + 14680064);   // 8.4 MB (sign-twisted q)
  unsigned short* kws = (unsigned short*)(ws + 23068672);   // 8.4 MB
  unsigned short* vtw = (unsigned short*)(ws + 39845888);   // 8.4 MB (v transposed)
  float*          rsw = (float*)(ws + 48234496);            // 128 KB rowsums

  k_convert<<<3584, 256, 0, stream>>>(query, Wq, Wk, Wv, xb, wb);
  k_proj<<<dim3(8, 32, 3), 256, 0, stream>>>(xb, wb, bq, bk, bv, qws, kws, vtw);
  k_attn_out<<<dim3(64, 16), 256, 0, stream>>>(qws, kws, vtw, outp, rsw);
  k_attn_mean<<<dim3(16, 16, 2), 256, 0, stream>>>(qws, kws, rsw, meanp);
}

// Round 4
// 137.238 us; speedup vs baseline: 1.7279x; 1.7279x over previous
//
#include <hip/hip_runtime.h>

typedef __attribute__((ext_vector_type(8))) __bf16 bf16x8;
typedef __attribute__((ext_vector_type(4))) __bf16 bf16x4;
typedef __attribute__((ext_vector_type(4))) float f32x4;
typedef __attribute__((ext_vector_type(8))) unsigned short us8;

constexpr float SCALE_L2E = 0.08838834764831845f * 1.4426950408889634f; // (1/sqrt(128))*log2(e)

__device__ __forceinline__ unsigned short f2bf(float f) {
  unsigned int u = __float_as_uint(f);
  u = (u + 0x7FFFu + ((u >> 16) & 1u)) >> 16;
  return (unsigned short)u;
}

__device__ __forceinline__ void gl_lds16(const void* g, void* l) {
  __builtin_amdgcn_global_load_lds(
      (__attribute__((address_space(1))) void*)const_cast<void*>(g),
      (__attribute__((address_space(3))) void*)l, 16, 0, 0);
}

// ---------------- K0: f32 -> bf16 convert (query + 3 weight matrices) ----------------
__global__ __launch_bounds__(256) void k_convert(
    const float* __restrict__ q, const float* __restrict__ wq,
    const float* __restrict__ wk, const float* __restrict__ wv,
    unsigned short* __restrict__ xb, unsigned short* __restrict__ wb) {
  long i = ((long)blockIdx.x * 256 + threadIdx.x) * 8;
  const float* s; unsigned short* d;
  if (i < 4194304)      { s = q  + i;             d = xb + i; }
  else if (i < 5242880) { s = wq + (i - 4194304); d = wb + (i - 4194304); }
  else if (i < 6291456) { s = wk + (i - 5242880); d = wb + 1048576 + (i - 5242880); }
  else                  { s = wv + (i - 6291456); d = wb + 2097152 + (i - 6291456); }
  float4 a = *(const float4*)s;
  float4 b = *(const float4*)(s + 4);
  us8 r;
  r[0]=f2bf(a.x); r[1]=f2bf(a.y); r[2]=f2bf(a.z); r[3]=f2bf(a.w);
  r[4]=f2bf(b.x); r[5]=f2bf(b.y); r[6]=f2bf(b.z); r[7]=f2bf(b.w);
  *(us8*)d = r;
}

// ---------------- K1: projection GEMM  C = X @ W^T + b  (z selects q/k/v) ----------------
// z==0 (q): sign twist applied, row-major out. z==1 (k): row-major out.
// z==2 (v): written DIRECTLY transposed into vt[bh*128+d][l] (packed 8B stores).
__global__ __launch_bounds__(256) void k_proj(
    const unsigned short* __restrict__ xb, const unsigned short* __restrict__ wb,
    const float* __restrict__ bq, const float* __restrict__ bk, const float* __restrict__ bv,
    unsigned short* __restrict__ oq, unsigned short* __restrict__ ok_, unsigned short* __restrict__ vt) {
  __shared__ unsigned short As[4096]; // 128 rows x 32 k
  __shared__ unsigned short Bs[4096];
  const int t = threadIdx.x;
  const int wave = t >> 6, lane = t & 63;
  const int lrow = lane & 15, grp = lane >> 4;
  const int z = blockIdx.z;
  const unsigned short* w = wb + (size_t)z * 1048576;
  const float* bias = (z == 0) ? bq : ((z == 1) ? bk : bv);

  const unsigned short* asrc = xb + ((size_t)(blockIdx.y * 128 + (t >> 2)) * 1024 + (t & 3) * 8);
  const unsigned short* bsrc = w  + ((size_t)(blockIdx.x * 128 + (t >> 2)) * 1024 + (t & 3) * 8);

  f32x4 acc[4][4] = {};
  for (int kt = 0; kt < 32; ++kt) {
    gl_lds16(asrc + kt*32,              &As[t*8]);
    gl_lds16(asrc + kt*32 + 64*1024,    &As[2048 + t*8]);
    gl_lds16(bsrc + kt*32,              &Bs[t*8]);
    gl_lds16(bsrc + kt*32 + 64*1024,    &Bs[2048 + t*8]);
    __syncthreads();
    const int wr = wave >> 1, wc = wave & 1;
    bf16x8 af[4], bf[4];
#pragma unroll
    for (int mf = 0; mf < 4; ++mf)
      af[mf] = *(const bf16x8*)&As[(wr*64 + mf*16 + lrow)*32 + grp*8];
#pragma unroll
    for (int nf = 0; nf < 4; ++nf)
      bf[nf] = *(const bf16x8*)&Bs[(wc*64 + nf*16 + lrow)*32 + grp*8];
#pragma unroll
    for (int mf = 0; mf < 4; ++mf)
#pragma unroll
      for (int nf = 0; nf < 4; ++nf)
        acc[mf][nf] = __builtin_amdgcn_mfma_f32_16x16x32_bf16(af[mf], bf[nf], acc[mf][nf], 0, 0, 0);
    __syncthreads();
  }
  const int wr = wave >> 1, wc = wave & 1;
  if (z == 2) {
#pragma unroll
    for (int nf = 0; nf < 4; ++nf) {
      const int col = blockIdx.x*128 + wc*64 + nf*16 + lrow;
      const int h = col >> 7, dc = col & 127;
      const float bsv = bias[col];
#pragma unroll
      for (int mf = 0; mf < 4; ++mf) {
        const int r0 = blockIdx.y*128 + wr*64 + mf*16 + grp*4;
        const int bb = r0 >> 11, l0 = r0 & 2047;
        bf16x4 pv;
#pragma unroll
        for (int i = 0; i < 4; ++i) pv[i] = (__bf16)(acc[mf][nf][i] + bsv);
        *(bf16x4*)&vt[((size_t)((bb*8 + h)*128 + dc))*2048 + l0] = pv;
      }
    }
  } else {
    unsigned short* dst = (z == 0) ? oq : ok_;
    const float sign = (z == 0 && (lane & 7) >= 4) ? -1.0f : 1.0f;
#pragma unroll
    for (int nf = 0; nf < 4; ++nf) {
      const int col = blockIdx.x*128 + wc*64 + nf*16 + lrow;
      const float bsv = bias[col];
#pragma unroll
      for (int mf = 0; mf < 4; ++mf)
#pragma unroll
        for (int i = 0; i < 4; ++i) {
          const int row = blockIdx.y*128 + wr*64 + mf*16 + grp*4 + i;
          dst[(size_t)row*1024 + col] = f2bf((acc[mf][nf][i] + bsv) * sign);
        }
    }
  }
}

// ---------------- K3: fused attention out + rowsum (no-max online softmax) ----------------
// QBLK=64, 512 blocks, XCD-swizzled (2 bh per XCD -> K/V L2-resident).
// 2-phase pipeline: K(64x128) + V(128x64) tiles double-buffered in LDS via
// global_load_lds (issued for tile mt+1 before computing mt); both tiles
// XOR-swizzled (inverse swizzle on global source, XOR on ds_read; LDS linear).
// Mid-iteration barrier drains lgkmcnt ONLY (prefetch stays in flight);
// vmcnt drained once per iteration after PV.
__global__ __launch_bounds__(256, 2) void k_attn_out(
    const unsigned short* __restrict__ qw, const unsigned short* __restrict__ kb,
    const unsigned short* __restrict__ vt, float* __restrict__ outp,
    float* __restrict__ rsw) {
  __shared__ unsigned short Ks[2][8192];   // 2 x 16 KB  [row 0..63][col 0..127] swizzled
  __shared__ unsigned short Vs[2][8192];   // 2 x 16 KB  [d 0..127][m 0..63] swizzled
  __shared__ unsigned short P[64*72];      // 9 KB [l][m], stride 72
  __shared__ float red[320];
  const int bid = blockIdx.x;
  const int xcd = bid & 7, slot = bid >> 3;
  const int bh = (xcd << 1) | (slot >> 5);   // 2 bh per XCD
  const int lt = slot & 31;                  // 64-row q tile index
  const int b = bh >> 3, h = bh & 7;
  const int t = threadIdx.x;
  const int wave = t >> 6, lane = t & 63;
  const int lrow = lane & 15, grp = lane >> 4;

  const unsigned short* qb  = qw + ((size_t)b*2048*1024 + (size_t)h*128);
  const unsigned short* kbp = kb + ((size_t)b*2048*1024 + (size_t)h*128);
  const unsigned short* vtp = vt + ((size_t)bh*128*2048);

  // staging source-address components (inverse swizzle lives on the global side)
  const int trow = t >> 4;                        // K: row-within-16
  const int ksc  = ((t & 15) ^ (trow & 7)) * 8;   // K swizzled source col (us)
  const int vrow = t >> 3;                        // V: row-within-32
  const int vsc  = ((t & 7) ^ (vrow & 7)) * 8;

  bf16x8 qf[4][4];
#pragma unroll
  for (int lf = 0; lf < 4; ++lf) {
    const size_t roff = (size_t)(lt*64 + lf*16 + lrow) * 1024;
#pragma unroll
    for (int ks = 0; ks < 4; ++ks)
      qf[lf][ks] = *(const bf16x8*)&qb[roff + ks*32 + grp*8];
  }

  f32x4 oacc[4][2] = {};
  float rs[4] = {0.f, 0.f, 0.f, 0.f};

  auto STAGE = [&](int buf, int mt) {
    const unsigned short* kt = kbp + (size_t)mt*64*1024;
#pragma unroll
    for (int i = 0; i < 4; ++i)
      gl_lds16(kt + (size_t)(i*16 + trow)*1024 + ksc, &Ks[buf][(i*256 + t)*8]);
    const unsigned short* vtile = vtp + mt*64;
#pragma unroll
    for (int i = 0; i < 4; ++i)
      gl_lds16(vtile + (size_t)(i*32 + vrow)*2048 + vsc, &Vs[buf][(i*256 + t)*8]);
  };

  auto COMPUTE = [&](int buf, int mt) {
    (void)mt;
    const int krow = wave*16 + lrow;
    bf16x8 kf[4];
#pragma unroll
    for (int ks = 0; ks < 4; ++ks)
      kf[ks] = *(const bf16x8*)&Ks[buf][krow*128 + (((ks*4 + grp) ^ (krow & 7)) << 3)];
    f32x4 s[4] = {};
#pragma unroll
    for (int ks = 0; ks < 4; ++ks)
#pragma unroll
      for (int lf = 0; lf < 4; ++lf)
        s[lf] = __builtin_amdgcn_mfma_f32_16x16x32_bf16(kf[ks], qf[lf][ks], s[lf], 0, 0, 0);
#pragma unroll
    for (int lf = 0; lf < 4; ++lf) {
      float e0 = __builtin_amdgcn_exp2f(s[lf][0] * SCALE_L2E);
      float e1 = __builtin_amdgcn_exp2f(s[lf][1] * SCALE_L2E);
      float e2 = __builtin_amdgcn_exp2f(s[lf][2] * SCALE_L2E);
      float e3 = __builtin_amdgcn_exp2f(s[lf][3] * SCALE_L2E);
      rs[lf] += (e0 + e1) + (e2 + e3);
      bf16x4 pk;
      pk[0] = (__bf16)e0; pk[1] = (__bf16)e1; pk[2] = (__bf16)e2; pk[3] = (__bf16)e3;
      *(bf16x4*)&P[(lf*16 + lrow)*72 + wave*16 + grp*4] = pk;
    }
    // barrier 1: P visible; ds ops only -> do NOT drain vmcnt (prefetch in flight)
    asm volatile("s_waitcnt lgkmcnt(0)" ::: "memory");
    __builtin_amdgcn_sched_barrier(0);
    __builtin_amdgcn_s_barrier();
#pragma unroll
    for (int ks2 = 0; ks2 < 2; ++ks2) {
      bf16x8 pa[4];
#pragma unroll
      for (int lf = 0; lf < 4; ++lf)
        pa[lf] = *(const bf16x8*)&P[(lf*16 + lrow)*72 + ks2*32 + grp*8];
#pragma unroll
      for (int df = 0; df < 2; ++df) {
        const int dd = wave*32 + df*16 + lrow;
        bf16x8 vf = *(const bf16x8*)&Vs[buf][dd*64 + (((ks2*4 + grp) ^ (dd & 7)) << 3)];
#pragma unroll
        for (int lf = 0; lf < 4; ++lf)
          oacc[lf][df] = __builtin_amdgcn_mfma_f32_16x16x32_bf16(pa[lf], vf, oacc[lf][df], 0, 0, 0);
      }
    }
    // barrier 2: next tile's staging landed (vmcnt) + this iter's P reads done (lgkm)
    asm volatile("s_waitcnt vmcnt(0) lgkmcnt(0)" ::: "memory");
    __builtin_amdgcn_sched_barrier(0);
    __builtin_amdgcn_s_barrier();
  };

  STAGE(0, 0);
  asm volatile("s_waitcnt vmcnt(0)" ::: "memory");
  __builtin_amdgcn_sched_barrier(0);
  __builtin_amdgcn_s_barrier();

  for (int mt = 0; mt < 32; mt += 2) {
    STAGE(1, mt + 1);
    COMPUTE(0, mt);
    if (mt + 2 < 32) STAGE(0, mt + 2);
    COMPUTE(1, mt + 1);
  }

#pragma unroll
  for (int lf = 0; lf < 4; ++lf) {
    rs[lf] += __shfl_xor(rs[lf], 16, 64);
    rs[lf] += __shfl_xor(rs[lf], 32, 64);
  }
  if (lane < 16) {
#pragma unroll
    for (int lf = 0; lf < 4; ++lf) red[wave*64 + lf*16 + lane] = rs[lf];
  }
  __syncthreads();
  if (t < 64) {
    float tot = (red[t] + red[64+t]) + (red[128+t] + red[192+t]);
    rsw[(size_t)bh*2048 + lt*64 + t] = tot;
    red[256 + t] = 1.0f / tot;
  }
  __syncthreads();
#pragma unroll
  for (int lf = 0; lf < 4; ++lf)
#pragma unroll
    for (int i = 0; i < 4; ++i) {
      const int l = lf*16 + grp*4 + i;
      const float iv = red[256 + l];
      const size_t rowo = (size_t)(b*2048 + lt*64 + l) * 1024 + h*128;
#pragma unroll
      for (int df = 0; df < 2; ++df)
        outp[rowo + wave*32 + df*16 + lrow] = oacc[lf][df][i] * iv;
    }
}

// ---------------- K4: head-mean attention weights (LDS-staged GEMM version) ----------------
__global__ __launch_bounds__(256) void k_attn_mean(
    const unsigned short* __restrict__ qw, const unsigned short* __restrict__ kb,
    const float* __restrict__ rsw, float* __restrict__ meanp) {
  __shared__ unsigned short Qs[128*128];   // 32 KB
  __shared__ unsigned short Ks[128*128];   // 32 KB
  __shared__ float inv_s[8*128];           // 4 KB
  const int mt = blockIdx.x;   // 0..15
  const int lt = blockIdx.y;   // 0..15
  const int b  = blockIdx.z;   // 0..1
  const int t = threadIdx.x;
  const int wave = t >> 6, lane = t & 63;
  const int lrow = lane & 15, grp = lane >> 4;
  const int wl = wave >> 1, wm = wave & 1;
  const int trow = t >> 4;     // 0..15 (staging row-within-16)
  const int tcol = t & 15;     // staging 16B-granule column

  for (int idx = t; idx < 1024; idx += 256) {
    int hh = idx >> 7, ll = idx & 127;
    inv_s[idx] = 1.0f / rsw[(size_t)(b*8 + hh)*2048 + lt*128 + ll];
  }

  f32x4 acc[4][4] = {};

  for (int h = 0; h < 8; ++h) {
    __syncthreads();
    const unsigned short* qbase = qw + ((size_t)(b*2048 + lt*128) * 1024 + h*128);
    const unsigned short* kbase = kb + ((size_t)(b*2048 + mt*128) * 1024 + h*128);
#pragma unroll
    for (int i = 0; i < 8; ++i) {
      const int row = i*16 + trow;
      const int sc = (tcol ^ (row & 7)) * 8;
      gl_lds16(qbase + (size_t)row*1024 + sc, &Qs[i*2048 + t*8]);
      gl_lds16(kbase + (size_t)row*1024 + sc, &Ks[i*2048 + t*8]);
    }
    __syncthreads();

    f32x4 s[4][4] = {};
#pragma unroll
    for (int ks = 0; ks < 4; ++ks) {
      bf16x8 af[4], bf[4];
#pragma unroll
      for (int lf = 0; lf < 4; ++lf) {
        const int row = wl*64 + lf*16 + lrow;
        af[lf] = *(const bf16x8*)&Qs[row*128 + ((ks*32 + grp*8) ^ ((row & 7) << 3))];
      }
#pragma unroll
      for (int mf = 0; mf < 4; ++mf) {
        const int row = wm*64 + mf*16 + lrow;
        bf[mf] = *(const bf16x8*)&Ks[row*128 + ((ks*32 + grp*8) ^ ((row & 7) << 3))];
      }
#pragma unroll
      for (int lf = 0; lf < 4; ++lf)
#pragma unroll
        for (int mf = 0; mf < 4; ++mf)
          s[lf][mf] = __builtin_amdgcn_mfma_f32_16x16x32_bf16(af[lf], bf[mf], s[lf][mf], 0, 0, 0);
    }
#pragma unroll
    for (int lf = 0; lf < 4; ++lf)
#pragma unroll
      for (int i = 0; i < 4; ++i) {
        const float iv = inv_s[h*128 + wl*64 + lf*16 + grp*4 + i];
#pragma unroll
        for (int mf = 0; mf < 4; ++mf)
          acc[lf][mf][i] += __builtin_amdgcn_exp2f(s[lf][mf][i] * SCALE_L2E) * iv;
      }
  }

#pragma unroll
  for (int lf = 0; lf < 4; ++lf)
#pragma unroll
    for (int i = 0; i < 4; ++i) {
      const int l = lt*128 + wl*64 + lf*16 + grp*4 + i;
      const size_t rowo = (size_t)(b*2048 + l) * 2048;
#pragma unroll
      for (int mf = 0; mf < 4; ++mf)
        meanp[rowo + mt*128 + wm*64 + mf*16 + lrow] = acc[lf][mf][i] * 0.125f;
    }
}

extern "C" void kernel_launch(void* const* d_in, const int* in_sizes, int n_in,
                              void* d_out, int out_size, void* d_ws, size_t ws_size,
                              hipStream_t stream) {
  (void)in_sizes; (void)n_in; (void)out_size; (void)ws_size;
  const float* query = (const float*)d_in[0];
  const float* Wq = (const float*)d_in[1];
  const float* bq = (const float*)d_in[2];
  const float* Wk = (const float*)d_in[3];
  const float* bk = (const float*)d_in[4];
  const float* Wv = (const float*)d_in[5];
  const float* bv = (const float*)d_in[6];
  float* outp  = (float*)d_out;
  float* meanp = outp + 4194304;           // (B,L,DM) then (B,L,L)

  char* ws = (char*)d_ws;
  unsigned short* xb  = (unsigned short*)(ws);              // 8.4 MB
  unsigned short* wb  = (unsigned short*)(ws + 8388608);    // 6.3 MB (Wq,Wk,Wv)
  unsigned short* qws = (unsigned short*)(ws + 14680064);   // 8.4 MB (sign-twisted q)
  unsigned short* kws = (unsigned short*)(ws + 23068672);   // 8.4 MB
  unsigned short* vtw = (unsigned short*)(ws + 39845888);   // 8.4 MB (v transposed)
  float*          rsw = (float*)(ws + 48234496);            // 128 KB rowsums

  k_convert<<<3584, 256, 0, stream>>>(query, Wq, Wk, Wv, xb, wb);
  k_proj<<<dim3(8, 32, 3), 256, 0, stream>>>(xb, wb, bq, bk, bv, qws, kws, vtw);
  k_attn_out<<<512, 256, 0, stream>>>(qws, kws, vtw, outp, rsw);
  k_attn_mean<<<dim3(16, 16, 2), 256, 0, stream>>>(qws, kws, rsw, meanp);
}